// Round 19
// baseline (419.088 us; speedup 1.0000x reference)
//
#include <hip/hip_runtime.h>
#include <cmath>

// Problem constants (B=4, S=4096, D=4096, E=64, K=8)
#define NTOK 16384
#define DDIM 4096
#define NEXP 64
#define TOPK 8
#define TPB   256               // tokens per block (bulk)
#define NKS   8                 // K-split ways across blocks
#define KSL   (DDIM / NKS)      // 512 k per slice
#define BK    32                // K per staged step
#define NSTEP (KSL / BK)        // 16
#define EPS_GAP 6e-5f           // ambiguity margin; trunc-split sigma ~3e-6 (20x)

typedef __attribute__((ext_vector_type(8))) short short8;   // 8 bf16
typedef __attribute__((ext_vector_type(4))) float f32x4;

__device__ __forceinline__ void gload16(const void* g, void* l) {
    __builtin_amdgcn_global_load_lds(
        (const __attribute__((address_space(1))) unsigned int*)g,
        (__attribute__((address_space(3))) unsigned int*)l, 16, 0, 0);
}

// trunc split: hi = top 16 bits (residual exact), lo = trunc16(f - hi).
#define CVT1(f, hOut, lOut, j) do {                                          \
    unsigned _u = __builtin_bit_cast(unsigned, (float)(f));                  \
    float _hf = __builtin_bit_cast(float, _u & 0xFFFF0000u);                 \
    hOut[j] = (short)(_u >> 16);                                             \
    lOut[j] = (short)(__builtin_bit_cast(unsigned, (float)((f) - _hf)) >> 16);\
} while (0)
#define CONV8(vA, vB, hOut, lOut) do {                       \
    CVT1(vA.x, hOut, lOut, 0); CVT1(vA.y, hOut, lOut, 1);    \
    CVT1(vA.z, hOut, lOut, 2); CVT1(vA.w, hOut, lOut, 3);    \
    CVT1(vB.x, hOut, lOut, 4); CVT1(vB.y, hOut, lOut, 5);    \
    CVT1(vB.z, hOut, lOut, 6); CVT1(vB.w, hOut, lOut, 7);    \
} while (0)

// ---------------------------------------------------------------------------
// Kernel 0 (verified): W -> lane-ordered bf16 hi/lo blob + zero all counters.
// ---------------------------------------------------------------------------
__global__ __launch_bounds__(256) void prep_w(const float* __restrict__ W,
                                              unsigned char* __restrict__ blob,
                                              int* __restrict__ cnts,
                                              int* __restrict__ tokgc)
{
    __shared__ float tile[32][65];
    const int c = blockIdx.x;
    const int t = threadIdx.x;
    if (c == 0 && t < 4) cnts[t] = 0;
    if (c == 1 && t < 64) tokgc[t] = 0;
    {
        const int r = t >> 3, q = t & 7;
        float4 v0 = *reinterpret_cast<const float4*>(
            &W[(size_t)(c * 32 + r) * NEXP + q * 8]);
        float4 v1 = *reinterpret_cast<const float4*>(
            &W[(size_t)(c * 32 + r) * NEXP + q * 8 + 4]);
        tile[r][q * 8 + 0] = v0.x; tile[r][q * 8 + 1] = v0.y;
        tile[r][q * 8 + 2] = v0.z; tile[r][q * 8 + 3] = v0.w;
        tile[r][q * 8 + 4] = v1.x; tile[r][q * 8 + 5] = v1.y;
        tile[r][q * 8 + 6] = v1.z; tile[r][q * 8 + 7] = v1.w;
    }
    __syncthreads();
    {
        const int el   = t & 15;
        const int kgrp = (t >> 4) & 3;
        const int n    = t >> 6;
        short8 hv, lv;
#pragma unroll
        for (int j = 0; j < 8; ++j) {
            float f = tile[kgrp * 8 + j][n * 16 + el];
            CVT1(f, hv, lv, j);
        }
        unsigned char* base = blob + (size_t)c * 8192 + n * 2048 +
                              (kgrp * 16 + el) * 16;
        *reinterpret_cast<short8*>(base)        = hv;   // hi
        *reinterpret_cast<short8*>(base + 1024) = lv;   // lo
    }
}

// ---------------------------------------------------------------------------
// Kernel 1: traffic-minimal bulk GEMM (R16/R17 verified) + FUSED COMBINE.
// Grid 512 = 64 tokgrp x 8 K-slices. After partial write, the LAST block of
// each tokgrp (device-scope fence + atomic count) combines all 8 slices in
// FIXED order (deterministic), reusing its dead 80KB LDS: bias + sigmoid +
// s_out + top-10 + flag. Removes the separate combine kernel + launch gap.
// ---------------------------------------------------------------------------
__global__ __launch_bounds__(512, 4) void bulk_kernel(
    const float* __restrict__ x, const unsigned char* __restrict__ blob,
    const float* __restrict__ b, float* __restrict__ part,
    float* __restrict__ g_out, float* __restrict__ i_out,
    float* __restrict__ s_out,
    int* __restrict__ tokgc,
    int* __restrict__ flag_cnt, int* __restrict__ flag_list, int cap)
{
    __shared__ __align__(16) unsigned char smem[81920];  // exactly 2 blocks/CU

    const int tid  = threadIdx.x;
    const int l    = tid & 63;
    const int w    = tid >> 6;
    const int tokg = blockIdx.x >> 3;
    const int ks   = blockIdx.x & 7;
    const int tok0 = tokg * TPB;

    // ---- stager: instr q covers tokens [q*64,q*64+64); per-lane pre-swizzle
#define DECLA(q) const float* aSrc##q = x +                                   \
    (size_t)(tok0 + q * 64 + (tid >> 3)) * DDIM + ks * KSL +                  \
    ((((tid & 7) ^ ((tid >> 3) & 7))) << 2);
    DECLA(0) DECLA(1) DECLA(2) DECLA(3)
#undef DECLA
    const unsigned char* bSrc = blob + (size_t)(ks * NSTEP) * 8192 + tid * 16;

#define STAGE(buf, c) do {                                                    \
    unsigned char* _a = smem + (buf) * 32768;                                 \
    gload16(aSrc0 + (size_t)(c) * BK, _a + 0 * 8192 + tid * 16);              \
    gload16(aSrc1 + (size_t)(c) * BK, _a + 1 * 8192 + tid * 16);              \
    gload16(aSrc2 + (size_t)(c) * BK, _a + 2 * 8192 + tid * 16);              \
    gload16(aSrc3 + (size_t)(c) * BK, _a + 3 * 8192 + tid * 16);              \
    gload16(bSrc + (size_t)(c) * 8192, smem + 65536 + (buf) * 8192 + tid * 16);\
} while (0)

    // ---- compute-lane constants ----
    const int mt   = l & 15;
    const int kgrp = l >> 4;
    const int sw   = mt & 7;
    const int row0 = w * 32 + mt;
    const int row1 = row0 + 16;
    const int aoff00 = row0 * 128 + (((kgrp * 2    ) ^ sw) << 4);
    const int aoff01 = row0 * 128 + (((kgrp * 2 + 1) ^ sw) << 4);
    const int aoff10 = row1 * 128 + (((kgrp * 2    ) ^ sw) << 4);
    const int aoff11 = row1 * 128 + (((kgrp * 2 + 1) ^ sw) << 4);

    f32x4 acc00 = (f32x4){0.f,0.f,0.f,0.f}, acc01 = acc00, acc02 = acc00, acc03 = acc00;
    f32x4 acc10 = acc00, acc11 = acc00, acc12 = acc00, acc13 = acc00;

#define MFMA3(accv, AH, AL, BH, BL) do {                                      \
    accv = __builtin_amdgcn_mfma_f32_16x16x32_bf16(AH, BH, accv, 0, 0, 0);    \
    accv = __builtin_amdgcn_mfma_f32_16x16x32_bf16(AH, BL, accv, 0, 0, 0);    \
    accv = __builtin_amdgcn_mfma_f32_16x16x32_bf16(AL, BH, accv, 0, 0, 0);    \
} while (0)

#define COMPUTE(buf) do {                                                     \
    const unsigned char* _a  = smem + (buf) * 32768;                          \
    const unsigned char* _bb = smem + 65536 + (buf) * 8192;                   \
    float4 A0 = *reinterpret_cast<const float4*>(_a + aoff00);                \
    float4 A1 = *reinterpret_cast<const float4*>(_a + aoff01);                \
    float4 A2 = *reinterpret_cast<const float4*>(_a + aoff10);                \
    float4 A3 = *reinterpret_cast<const float4*>(_a + aoff11);                \
    short8 ah0, al0, ah1, al1;                                                \
    CONV8(A0, A1, ah0, al0);                                                  \
    CONV8(A2, A3, ah1, al1);                                                  \
    {                                                                         \
        short8 bh = *reinterpret_cast<const short8*>(_bb + 0 * 2048 + l * 16);\
        short8 bl = *reinterpret_cast<const short8*>(_bb + 0 * 2048 + 1024 + l * 16);\
        MFMA3(acc00, ah0, al0, bh, bl); MFMA3(acc10, ah1, al1, bh, bl);       \
    }                                                                         \
    {                                                                         \
        short8 bh = *reinterpret_cast<const short8*>(_bb + 1 * 2048 + l * 16);\
        short8 bl = *reinterpret_cast<const short8*>(_bb + 1 * 2048 + 1024 + l * 16);\
        MFMA3(acc01, ah0, al0, bh, bl); MFMA3(acc11, ah1, al1, bh, bl);       \
    }                                                                         \
    {                                                                         \
        short8 bh = *reinterpret_cast<const short8*>(_bb + 2 * 2048 + l * 16);\
        short8 bl = *reinterpret_cast<const short8*>(_bb + 2 * 2048 + 1024 + l * 16);\
        MFMA3(acc02, ah0, al0, bh, bl); MFMA3(acc12, ah1, al1, bh, bl);       \
    }                                                                         \
    {                                                                         \
        short8 bh = *reinterpret_cast<const short8*>(_bb + 3 * 2048 + l * 16);\
        short8 bl = *reinterpret_cast<const short8*>(_bb + 3 * 2048 + 1024 + l * 16);\
        MFMA3(acc03, ah0, al0, bh, bl); MFMA3(acc13, ah1, al1, bh, bl);       \
    }                                                                         \
} while (0)

    // ---- counted-vmcnt pipeline (R17) ----
    STAGE(0, 0);
    STAGE(1, 1);
    for (int c = 0; c < NSTEP; ++c) {
        if (c < NSTEP - 1) {
            asm volatile("s_waitcnt vmcnt(5)\n\ts_barrier" ::: "memory");
        } else {
            asm volatile("s_waitcnt vmcnt(0)\n\ts_barrier" ::: "memory");
        }
        COMPUTE(c & 1);
        __builtin_amdgcn_s_barrier();
        if (c + 2 < NSTEP) STAGE(c & 1, c + 2);
    }

    // ---- write fp32 partials: part[ks][tok][exp] (verified C mapping) ----
#define WRPART(tf, n, accv) do {                                              \
    _Pragma("unroll")                                                         \
    for (int r = 0; r < 4; ++r)                                               \
        part[((size_t)ks * NTOK + tok0 + w * 32 + tf * 16 + kgrp * 4 + r)     \
             * NEXP + n * 16 + mt] = accv[r];                                 \
} while (0)
    WRPART(0, 0, acc00); WRPART(0, 1, acc01); WRPART(0, 2, acc02); WRPART(0, 3, acc03);
    WRPART(1, 0, acc10); WRPART(1, 1, acc11); WRPART(1, 2, acc12); WRPART(1, 3, acc13);
#undef WRPART
#undef STAGE
#undef COMPUTE
#undef MFMA3

    // ---- fused combine: last block of this tokgrp does it ----
    __threadfence();                          // release my partial stores
    __syncthreads();
    int* lastP = (int*)(smem + 81916);        // dead B-buf bytes (uniform bcast)
    if (tid == 0)
        *lastP = (atomicAdd(&tokgc[tokg], 1) == NKS - 1) ? 1 : 0;
    __syncthreads();
    if (!*lastP) return;
    __threadfence();                          // acquire others' stores

    float* ls = (float*)smem;                 // [256][68] = 69632 B
    {
        const int t   = tid >> 1;             // token 0..255
        const int eh2 = (tid & 1) * 32;       // expert half
#pragma unroll
        for (int g = 0; g < 8; ++g) {
            const int e = eh2 + g * 4;
            const size_t base = ((size_t)(tok0 + t)) * NEXP + e;
            float4 a = *reinterpret_cast<const float4*>(&part[base]);
#pragma unroll
            for (int s = 1; s < NKS; ++s) {   // FIXED order -> deterministic
                float4 v = *reinterpret_cast<const float4*>(
                    &part[(size_t)s * NTOK * NEXP + base]);
                a.x += v.x; a.y += v.y; a.z += v.z; a.w += v.w;
            }
            float4 bv = *reinterpret_cast<const float4*>(&b[e]);
            a.x += bv.x; a.y += bv.y; a.z += bv.z; a.w += bv.w;
            *reinterpret_cast<float4*>(&ls[t * 68 + e]) = a;
            float4 sv;
            sv.x = 1.0f / (1.0f + __expf(-a.x));
            sv.y = 1.0f / (1.0f + __expf(-a.y));
            sv.z = 1.0f / (1.0f + __expf(-a.z));
            sv.w = 1.0f / (1.0f + __expf(-a.w));
            *reinterpret_cast<float4*>(&s_out[base]) = sv;
        }
    }
    __syncthreads();

    if (tid < TPB) {                          // top-10 scan, one lane/token
        const int t = tid;
        float val[10];
        int   idx[10];
#pragma unroll
        for (int j = 0; j < 10; ++j) { val[j] = -1e30f; idx[j] = 0; }
        for (int e = 0; e < NEXP; ++e) {
            float v = ls[t * 68 + e];
            int  ei = e;
#pragma unroll
            for (int j = 0; j < 10; ++j) {
                if (v > val[j]) {   // strict > keeps lower index first on ties
                    float tv = val[j]; val[j] = v; v = tv;
                    int   ti = idx[j]; idx[j] = ei; ei = ti;
                }
            }
        }
        bool flag = false;
#pragma unroll
        for (int j = 0; j < 9; ++j) flag |= (val[j] - val[j + 1]) < EPS_GAP;

        float gg[TOPK], gsum = 0.0f;
#pragma unroll
        for (int j = 0; j < TOPK; ++j) {
            gg[j] = 1.0f / (1.0f + __expf(-val[j]));
            gsum += gg[j];
        }
        const float inv = 1.0f / gsum;
        const int tglob = tok0 + t;
#pragma unroll
        for (int j = 0; j < TOPK; ++j) {
            g_out[(size_t)tglob * TOPK + j] = gg[j] * inv;
            i_out[(size_t)tglob * TOPK + j] = (float)idx[j];
        }
        if (flag) {
            int p = atomicAdd(flag_cnt, 1);
            if (p < cap) flag_list[p] = tglob;
        }
    }
}

// ---------------------------------------------------------------------------
// Kernel 2: f64-exact re-rank of ambiguous tokens (verified).
// ---------------------------------------------------------------------------
__global__ __launch_bounds__(256) void refine64(
    const float* __restrict__ x, const float* __restrict__ W,
    const float* __restrict__ b, float* __restrict__ g_out,
    float* __restrict__ i_out, float* __restrict__ s_out,
    const int* __restrict__ flag_cnt, const int* __restrict__ flag_list,
    int flag_cap)
{
    __shared__ float  xs2[DDIM];
    __shared__ double red[4][NEXP];
    __shared__ double sc[NEXP];

    const int tid = threadIdx.x;
    int count = *flag_cnt;
    if (count > flag_cap) count = flag_cap;

    for (int it = blockIdx.x; it < count; it += gridDim.x) {
        const int tok = flag_list[it];
        __syncthreads();
#pragma unroll
        for (int q = 0; q < 4; ++q) {
            int fi = tid + 256 * q;
            *reinterpret_cast<float4*>(&xs2[fi * 4]) =
                *reinterpret_cast<const float4*>(&x[(size_t)tok * DDIM + fi * 4]);
        }
        __syncthreads();

        const int e    = tid & 63;
        const int pt   = tid >> 6;
        const int dbase = pt * (DDIM / 4);
        double a = 0.0;
        for (int d = 0; d < DDIM / 4; ++d) {
            a = fma((double)xs2[dbase + d],
                    (double)W[(size_t)(dbase + d) * NEXP + e], a);
        }
        red[pt][e] = a;
        __syncthreads();

        if (tid < NEXP) {
            double z = ((red[0][tid] + red[1][tid]) +
                        (red[2][tid] + red[3][tid])) + (double)b[tid];
            double s = 1.0 / (1.0 + exp(-z));
            sc[tid] = s;
            s_out[(size_t)tok * NEXP + tid] = (float)s;
        }
        __syncthreads();

        if (tid == 0) {
            double val[TOPK];
            int    idx[TOPK];
#pragma unroll
            for (int j = 0; j < TOPK; ++j) { val[j] = -1e30; idx[j] = 0; }
            for (int e2 = 0; e2 < NEXP; ++e2) {
                double v = sc[e2];
                int   ei = e2;
#pragma unroll
                for (int j = 0; j < TOPK; ++j) {
                    if (v > val[j]) {
                        double tv = val[j]; val[j] = v; v = tv;
                        int    ti = idx[j]; idx[j] = ei; ei = ti;
                    }
                }
            }
            double gsum = 0.0;
#pragma unroll
            for (int j = 0; j < TOPK; ++j) gsum += val[j];
            const double inv = 1.0 / gsum;
#pragma unroll
            for (int j = 0; j < TOPK; ++j) {
                g_out[(size_t)tok * TOPK + j] = (float)(val[j] * inv);
                i_out[(size_t)tok * TOPK + j] = (float)idx[j];
            }
        }
        __syncthreads();
    }
}

// ---------------------------------------------------------------------------
extern "C" void kernel_launch(void* const* d_in, const int* in_sizes, int n_in,
                              void* d_out, int out_size, void* d_ws, size_t ws_size,
                              hipStream_t stream)
{
    (void)in_sizes; (void)n_in; (void)out_size;
    const float* x = (const float*)d_in[0];
    const float* W = (const float*)d_in[1];
    const float* b = (const float*)d_in[2];

    float* g_out = (float*)d_out;                       // [NTOK, 8]
    float* i_out = g_out + (size_t)NTOK * TOPK;         // [NTOK, 8] indices as float
    float* s_out = i_out + (size_t)NTOK * TOPK;         // [NTOK, 64]

    const size_t OFF_TGC  = 256;
    const size_t OFF_LIST = 1024;
    const size_t OFF_BLOB = 131072;
    const size_t OFF_PART = OFF_BLOB + 128u * 8192u;            // +1 MB
    const size_t WS_NEED  = OFF_PART + (size_t)NKS * NTOK * NEXP * 4;  // +32 MB
    if (ws_size < WS_NEED) return;

    char* ws = (char*)d_ws;
    int* cnt   = (int*)ws;
    int* tokgc = (int*)(ws + OFF_TGC);
    int* list  = (int*)(ws + OFF_LIST);
    unsigned char* blob = (unsigned char*)(ws + OFF_BLOB);
    float* part = (float*)(ws + OFF_PART);
    int cap = NTOK;

    prep_w<<<128, 256, 0, stream>>>(W, blob, cnt, tokgc);
    bulk_kernel<<<(NTOK / TPB) * NKS, 512, 0, stream>>>(
        x, blob, b, part, g_out, i_out, s_out, tokgc, cnt, list, cap);
    refine64<<<64, 256, 0, stream>>>(x, W, b, g_out, i_out, s_out,
                                     cnt, list, cap);
}

// Round 20
// 158.258 us; speedup vs baseline: 2.6481x; 2.6481x over previous
//
#include <hip/hip_runtime.h>
#include <cmath>

// Problem constants (B=4, S=4096, D=4096, E=64, K=8)
#define NTOK 16384
#define DDIM 4096
#define NEXP 64
#define TOPK 8
#define TPB   256               // tokens per block (bulk)
#define NKS   8                 // K-split ways across blocks
#define KSL   (DDIM / NKS)      // 512 k per slice
#define BK    32                // K per staged step
#define NSTEP (KSL / BK)        // 16
#define EPS_GAP 6e-5f           // ambiguity margin; trunc-split sigma ~3e-6 (20x)

typedef __attribute__((ext_vector_type(8))) short short8;   // 8 bf16
typedef __attribute__((ext_vector_type(4))) float f32x4;

__device__ __forceinline__ void gload16(const void* g, void* l) {
    __builtin_amdgcn_global_load_lds(
        (const __attribute__((address_space(1))) unsigned int*)g,
        (__attribute__((address_space(3))) unsigned int*)l, 16, 0, 0);
}

// trunc split: hi = top 16 bits (residual exact), lo = trunc16(f - hi).
#define CVT1(f, hOut, lOut, j) do {                                          \
    unsigned _u = __builtin_bit_cast(unsigned, (float)(f));                  \
    float _hf = __builtin_bit_cast(float, _u & 0xFFFF0000u);                 \
    hOut[j] = (short)(_u >> 16);                                             \
    lOut[j] = (short)(__builtin_bit_cast(unsigned, (float)((f) - _hf)) >> 16);\
} while (0)
#define CONV8(vA, vB, hOut, lOut) do {                       \
    CVT1(vA.x, hOut, lOut, 0); CVT1(vA.y, hOut, lOut, 1);    \
    CVT1(vA.z, hOut, lOut, 2); CVT1(vA.w, hOut, lOut, 3);    \
    CVT1(vB.x, hOut, lOut, 4); CVT1(vB.y, hOut, lOut, 5);    \
    CVT1(vB.z, hOut, lOut, 6); CVT1(vB.w, hOut, lOut, 7);    \
} while (0)

// ---------------------------------------------------------------------------
// Kernel 0 (verified): W -> lane-ordered bf16 hi/lo blob.
// blob[c32 0..127][n 0..3][granule=lane 0..63][16B], lo at +1024 within n.
// Consumer lane l: expert e = n*16+(l&15), k = c*32+(l>>4)*8+j.
// ---------------------------------------------------------------------------
__global__ __launch_bounds__(256) void prep_w(const float* __restrict__ W,
                                              unsigned char* __restrict__ blob,
                                              int* __restrict__ cnts)
{
    __shared__ float tile[32][65];
    const int c = blockIdx.x;
    const int t = threadIdx.x;
    if (c == 0 && t < 4) cnts[t] = 0;
    {
        const int r = t >> 3, q = t & 7;
        float4 v0 = *reinterpret_cast<const float4*>(
            &W[(size_t)(c * 32 + r) * NEXP + q * 8]);
        float4 v1 = *reinterpret_cast<const float4*>(
            &W[(size_t)(c * 32 + r) * NEXP + q * 8 + 4]);
        tile[r][q * 8 + 0] = v0.x; tile[r][q * 8 + 1] = v0.y;
        tile[r][q * 8 + 2] = v0.z; tile[r][q * 8 + 3] = v0.w;
        tile[r][q * 8 + 4] = v1.x; tile[r][q * 8 + 5] = v1.y;
        tile[r][q * 8 + 6] = v1.z; tile[r][q * 8 + 7] = v1.w;
    }
    __syncthreads();
    {
        const int el   = t & 15;
        const int kgrp = (t >> 4) & 3;
        const int n    = t >> 6;
        short8 hv, lv;
#pragma unroll
        for (int j = 0; j < 8; ++j) {
            float f = tile[kgrp * 8 + j][n * 16 + el];
            CVT1(f, hv, lv, j);
        }
        unsigned char* base = blob + (size_t)c * 8192 + n * 2048 +
                              (kgrp * 16 + el) * 16;
        *reinterpret_cast<short8*>(base)        = hv;   // hi
        *reinterpret_cast<short8*>(base + 1024) = lv;   // lo
    }
}

// ---------------------------------------------------------------------------
// Kernel 1: traffic-minimal bulk GEMM + counted-vmcnt pipeline (verified,
// 158.9 us total). Grid 512 = 64 tokgrp x 8 K-slices (2 blocks/CU).
// Block = 256 tok x 64 exp x 512-k slice, BK=32 -> 16 steps.
// ---------------------------------------------------------------------------
__global__ __launch_bounds__(512, 4) void bulk_kernel(
    const float* __restrict__ x, const unsigned char* __restrict__ blob,
    float* __restrict__ part)
{
    __shared__ __align__(16) unsigned char smem[81920];

    const int tid  = threadIdx.x;
    const int l    = tid & 63;
    const int w    = tid >> 6;
    const int tokg = blockIdx.x >> 3;
    const int ks   = blockIdx.x & 7;
    const int tok0 = tokg * TPB;

    // ---- stager: instr q covers tokens [q*64,q*64+64); per-lane pre-swizzle
#define DECLA(q) const float* aSrc##q = x +                                   \
    (size_t)(tok0 + q * 64 + (tid >> 3)) * DDIM + ks * KSL +                  \
    ((((tid & 7) ^ ((tid >> 3) & 7))) << 2);
    DECLA(0) DECLA(1) DECLA(2) DECLA(3)
#undef DECLA
    const unsigned char* bSrc = blob + (size_t)(ks * NSTEP) * 8192 + tid * 16;

#define STAGE(buf, c) do {                                                    \
    unsigned char* _a = smem + (buf) * 32768;                                 \
    gload16(aSrc0 + (size_t)(c) * BK, _a + 0 * 8192 + tid * 16);              \
    gload16(aSrc1 + (size_t)(c) * BK, _a + 1 * 8192 + tid * 16);              \
    gload16(aSrc2 + (size_t)(c) * BK, _a + 2 * 8192 + tid * 16);              \
    gload16(aSrc3 + (size_t)(c) * BK, _a + 3 * 8192 + tid * 16);              \
    gload16(bSrc + (size_t)(c) * 8192, smem + 65536 + (buf) * 8192 + tid * 16);\
} while (0)

    // ---- compute-lane constants ----
    const int mt   = l & 15;
    const int kgrp = l >> 4;
    const int sw   = mt & 7;
    const int row0 = w * 32 + mt;
    const int row1 = row0 + 16;
    const int aoff00 = row0 * 128 + (((kgrp * 2    ) ^ sw) << 4);
    const int aoff01 = row0 * 128 + (((kgrp * 2 + 1) ^ sw) << 4);
    const int aoff10 = row1 * 128 + (((kgrp * 2    ) ^ sw) << 4);
    const int aoff11 = row1 * 128 + (((kgrp * 2 + 1) ^ sw) << 4);

    f32x4 acc00 = (f32x4){0.f,0.f,0.f,0.f}, acc01 = acc00, acc02 = acc00, acc03 = acc00;
    f32x4 acc10 = acc00, acc11 = acc00, acc12 = acc00, acc13 = acc00;

#define MFMA3(accv, AH, AL, BH, BL) do {                                      \
    accv = __builtin_amdgcn_mfma_f32_16x16x32_bf16(AH, BH, accv, 0, 0, 0);    \
    accv = __builtin_amdgcn_mfma_f32_16x16x32_bf16(AH, BL, accv, 0, 0, 0);    \
    accv = __builtin_amdgcn_mfma_f32_16x16x32_bf16(AL, BH, accv, 0, 0, 0);    \
} while (0)

#define COMPUTE(buf) do {                                                     \
    const unsigned char* _a  = smem + (buf) * 32768;                          \
    const unsigned char* _bb = smem + 65536 + (buf) * 8192;                   \
    float4 A0 = *reinterpret_cast<const float4*>(_a + aoff00);                \
    float4 A1 = *reinterpret_cast<const float4*>(_a + aoff01);                \
    float4 A2 = *reinterpret_cast<const float4*>(_a + aoff10);                \
    float4 A3 = *reinterpret_cast<const float4*>(_a + aoff11);                \
    short8 ah0, al0, ah1, al1;                                                \
    CONV8(A0, A1, ah0, al0);                                                  \
    CONV8(A2, A3, ah1, al1);                                                  \
    {                                                                         \
        short8 bh = *reinterpret_cast<const short8*>(_bb + 0 * 2048 + l * 16);\
        short8 bl = *reinterpret_cast<const short8*>(_bb + 0 * 2048 + 1024 + l * 16);\
        MFMA3(acc00, ah0, al0, bh, bl); MFMA3(acc10, ah1, al1, bh, bl);       \
    }                                                                         \
    {                                                                         \
        short8 bh = *reinterpret_cast<const short8*>(_bb + 1 * 2048 + l * 16);\
        short8 bl = *reinterpret_cast<const short8*>(_bb + 1 * 2048 + 1024 + l * 16);\
        MFMA3(acc01, ah0, al0, bh, bl); MFMA3(acc11, ah1, al1, bh, bl);       \
    }                                                                         \
    {                                                                         \
        short8 bh = *reinterpret_cast<const short8*>(_bb + 2 * 2048 + l * 16);\
        short8 bl = *reinterpret_cast<const short8*>(_bb + 2 * 2048 + 1024 + l * 16);\
        MFMA3(acc02, ah0, al0, bh, bl); MFMA3(acc12, ah1, al1, bh, bl);       \
    }                                                                         \
    {                                                                         \
        short8 bh = *reinterpret_cast<const short8*>(_bb + 3 * 2048 + l * 16);\
        short8 bl = *reinterpret_cast<const short8*>(_bb + 3 * 2048 + 1024 + l * 16);\
        MFMA3(acc03, ah0, al0, bh, bl); MFMA3(acc13, ah1, al1, bh, bl);       \
    }                                                                         \
} while (0)

    // ---- counted-vmcnt pipeline ----
    STAGE(0, 0);
    STAGE(1, 1);
    for (int c = 0; c < NSTEP; ++c) {
        if (c < NSTEP - 1) {
            asm volatile("s_waitcnt vmcnt(5)\n\ts_barrier" ::: "memory");
        } else {
            asm volatile("s_waitcnt vmcnt(0)\n\ts_barrier" ::: "memory");
        }
        COMPUTE(c & 1);
        __builtin_amdgcn_s_barrier();
        if (c + 2 < NSTEP) STAGE(c & 1, c + 2);
    }

    // ---- write fp32 partials: part[ks][tok][exp] (verified C mapping) ----
#define WRPART(tf, n, accv) do {                                              \
    _Pragma("unroll")                                                         \
    for (int r = 0; r < 4; ++r)                                               \
        part[((size_t)ks * NTOK + tok0 + w * 32 + tf * 16 + kgrp * 4 + r)     \
             * NEXP + n * 16 + mt] = accv[r];                                 \
} while (0)
    WRPART(0, 0, acc00); WRPART(0, 1, acc01); WRPART(0, 2, acc02); WRPART(0, 3, acc03);
    WRPART(1, 0, acc10); WRPART(1, 1, acc11); WRPART(1, 2, acc12); WRPART(1, 3, acc13);
#undef WRPART
#undef STAGE
#undef COMPUTE
#undef MFMA3
}

// ---------------------------------------------------------------------------
// Kernel 2: combine slices (fixed order) + bias + sigmoid + top-10 + flag.
// 256 blocks x 256 thr; block = 64 tokens.
// ---------------------------------------------------------------------------
__global__ __launch_bounds__(256) void combine_kernel(
    const float* __restrict__ part, const float* __restrict__ b,
    float* __restrict__ g_out, float* __restrict__ i_out,
    float* __restrict__ s_out,
    int* __restrict__ flag_cnt, int* __restrict__ flag_list, int cap)
{
    __shared__ float ls[64 * 68];
    const int tid  = threadIdx.x;
    const int tok0 = blockIdx.x * 64;
    const int t    = tid >> 2;
    const int e16  = (tid & 3) * 16;

#pragma unroll
    for (int g = 0; g < 4; ++g) {
        const int e = e16 + g * 4;
        const size_t base = ((size_t)(tok0 + t)) * NEXP + e;
        float4 a = *reinterpret_cast<const float4*>(&part[base]);
#pragma unroll
        for (int s = 1; s < NKS; ++s) {
            float4 v = *reinterpret_cast<const float4*>(
                &part[(size_t)s * NTOK * NEXP + base]);
            a.x += v.x; a.y += v.y; a.z += v.z; a.w += v.w;
        }
        float4 bv = *reinterpret_cast<const float4*>(&b[e]);
        a.x += bv.x; a.y += bv.y; a.z += bv.z; a.w += bv.w;
        *reinterpret_cast<float4*>(&ls[t * 68 + e]) = a;
        float4 sv;
        sv.x = 1.0f / (1.0f + __expf(-a.x));
        sv.y = 1.0f / (1.0f + __expf(-a.y));
        sv.z = 1.0f / (1.0f + __expf(-a.z));
        sv.w = 1.0f / (1.0f + __expf(-a.w));
        *reinterpret_cast<float4*>(&s_out[(size_t)(tok0 + t) * NEXP + e]) = sv;
    }
    __syncthreads();

    if (tid < 64) {
        const int tk = tid;
        float val[10];
        int   idx[10];
#pragma unroll
        for (int j = 0; j < 10; ++j) { val[j] = -1e30f; idx[j] = 0; }
        for (int e = 0; e < NEXP; ++e) {
            float v = ls[tk * 68 + e];
            int  ei = e;
#pragma unroll
            for (int j = 0; j < 10; ++j) {
                if (v > val[j]) {   // strict > keeps lower index first on ties
                    float tv = val[j]; val[j] = v; v = tv;
                    int   ti = idx[j]; idx[j] = ei; ei = ti;
                }
            }
        }
        bool flag = false;
#pragma unroll
        for (int j = 0; j < 9; ++j) flag |= (val[j] - val[j + 1]) < EPS_GAP;

        float gg[TOPK], gsum = 0.0f;
#pragma unroll
        for (int j = 0; j < TOPK; ++j) {
            gg[j] = 1.0f / (1.0f + __expf(-val[j]));
            gsum += gg[j];
        }
        const float inv = 1.0f / gsum;
        const int tglob = tok0 + tk;
#pragma unroll
        for (int j = 0; j < TOPK; ++j) {
            g_out[(size_t)tglob * TOPK + j] = gg[j] * inv;
            i_out[(size_t)tglob * TOPK + j] = (float)idx[j];
        }
        if (flag) {
            int p = atomicAdd(flag_cnt, 1);
            if (p < cap) flag_list[p] = tglob;
        }
    }
}

// ---------------------------------------------------------------------------
// Kernel 3: f64-exact re-rank of ambiguous tokens (verified).
// ---------------------------------------------------------------------------
__global__ __launch_bounds__(256) void refine64(
    const float* __restrict__ x, const float* __restrict__ W,
    const float* __restrict__ b, float* __restrict__ g_out,
    float* __restrict__ i_out, float* __restrict__ s_out,
    const int* __restrict__ flag_cnt, const int* __restrict__ flag_list,
    int flag_cap)
{
    __shared__ float  xs2[DDIM];
    __shared__ double red[4][NEXP];
    __shared__ double sc[NEXP];

    const int tid = threadIdx.x;
    int count = *flag_cnt;
    if (count > flag_cap) count = flag_cap;

    for (int it = blockIdx.x; it < count; it += gridDim.x) {
        const int tok = flag_list[it];
        __syncthreads();
#pragma unroll
        for (int q = 0; q < 4; ++q) {
            int fi = tid + 256 * q;
            *reinterpret_cast<float4*>(&xs2[fi * 4]) =
                *reinterpret_cast<const float4*>(&x[(size_t)tok * DDIM + fi * 4]);
        }
        __syncthreads();

        const int e    = tid & 63;
        const int pt   = tid >> 6;
        const int dbase = pt * (DDIM / 4);
        double a = 0.0;
        for (int d = 0; d < DDIM / 4; ++d) {
            a = fma((double)xs2[dbase + d],
                    (double)W[(size_t)(dbase + d) * NEXP + e], a);
        }
        red[pt][e] = a;
        __syncthreads();

        if (tid < NEXP) {
            double z = ((red[0][tid] + red[1][tid]) +
                        (red[2][tid] + red[3][tid])) + (double)b[tid];
            double s = 1.0 / (1.0 + exp(-z));
            sc[tid] = s;
            s_out[(size_t)tok * NEXP + tid] = (float)s;
        }
        __syncthreads();

        if (tid == 0) {
            double val[TOPK];
            int    idx[TOPK];
#pragma unroll
            for (int j = 0; j < TOPK; ++j) { val[j] = -1e30; idx[j] = 0; }
            for (int e2 = 0; e2 < NEXP; ++e2) {
                double v = sc[e2];
                int   ei = e2;
#pragma unroll
                for (int j = 0; j < TOPK; ++j) {
                    if (v > val[j]) {
                        double tv = val[j]; val[j] = v; v = tv;
                        int    ti = idx[j]; idx[j] = ei; ei = ti;
                    }
                }
            }
            double gsum = 0.0;
#pragma unroll
            for (int j = 0; j < TOPK; ++j) gsum += val[j];
            const double inv = 1.0 / gsum;
#pragma unroll
            for (int j = 0; j < TOPK; ++j) {
                g_out[(size_t)tok * TOPK + j] = (float)(val[j] * inv);
                i_out[(size_t)tok * TOPK + j] = (float)idx[j];
            }
        }
        __syncthreads();
    }
}

// ---------------------------------------------------------------------------
extern "C" void kernel_launch(void* const* d_in, const int* in_sizes, int n_in,
                              void* d_out, int out_size, void* d_ws, size_t ws_size,
                              hipStream_t stream)
{
    (void)in_sizes; (void)n_in; (void)out_size;
    const float* x = (const float*)d_in[0];
    const float* W = (const float*)d_in[1];
    const float* b = (const float*)d_in[2];

    float* g_out = (float*)d_out;                       // [NTOK, 8]
    float* i_out = g_out + (size_t)NTOK * TOPK;         // [NTOK, 8] indices as float
    float* s_out = i_out + (size_t)NTOK * TOPK;         // [NTOK, 64]

    const size_t OFF_LIST = 1024;
    const size_t OFF_BLOB = 131072;
    const size_t OFF_PART = OFF_BLOB + 128u * 8192u;            // +1 MB
    const size_t WS_NEED  = OFF_PART + (size_t)NKS * NTOK * NEXP * 4;  // +32 MB
    if (ws_size < WS_NEED) return;

    char* ws = (char*)d_ws;
    int* cnt  = (int*)ws;
    int* list = (int*)(ws + OFF_LIST);
    unsigned char* blob = (unsigned char*)(ws + OFF_BLOB);
    float* part = (float*)(ws + OFF_PART);
    int cap = NTOK;

    prep_w<<<128, 256, 0, stream>>>(W, blob, cnt);
    bulk_kernel<<<(NTOK / TPB) * NKS, 512, 0, stream>>>(x, blob, part);
    combine_kernel<<<NTOK / 64, 256, 0, stream>>>(part, b, g_out, i_out, s_out,
                                                  cnt, list, cap);
    refine64<<<256, 256, 0, stream>>>(x, W, b, g_out, i_out, s_out,
                                      cnt, list, cap);
}